// Round 12
// baseline (115.319 us; speedup 1.0000x reference)
//
#include <hip/hip_runtime.h>
#include <hip/hip_bf16.h>

typedef __attribute__((ext_vector_type(4))) float  f32x4;
typedef __attribute__((ext_vector_type(8))) short  bf16x8;
typedef __attribute__((ext_vector_type(4))) short  bf16x4;

#define DIM       256
#define NBLOCKS   256
#define NTHREADS  512
#define NROUNDS   16           // 64-token rounds per block (1024 tokens)
#define LDS_BYTES 131072       // W staging (128 KB), later overlaid by 2x32 KB A-bufs

#define WAITV(N) asm volatile("s_waitcnt vmcnt(" #N ")" ::: "memory")

__device__ __forceinline__ short f2bf(float x) {
    __hip_bfloat16 h = __float2bfloat16(x);
    return *reinterpret_cast<short*>(&h);
}

// Pinned-issue load; vmcnt retires FIFO (m135), so counted waits are exact.
__device__ __forceinline__ f32x4 gload4(const float* p) {
    f32x4 r;
    asm volatile("global_load_dwordx4 %0, %1, off" : "=v"(r) : "v"(p) : "memory");
    return r;
}

// out[n][o] = sum_k X[n][k] * W0[o][k]  (router is degenerate: expert 0 always)
__global__ __launch_bounds__(NTHREADS, 2)   // 256-VGPR cap (round-8 lesson)
void moe_expert0_kernel(const float* __restrict__ X,
                        const float* __restrict__ W0,
                        float* __restrict__ Out)
{
    extern __shared__ char lds[];
    const int tid  = threadIdx.x;
    const int lane = tid & 63;
    const int wave = tid >> 6;
    const int b    = blockIdx.x;

    // ---- stage full W (256x256) -> bf16, XOR-swizzled: row*512 + (cb ^ ((row&15)<<4))
    #pragma unroll
    for (int i = 0; i < 16; ++i) {
        int chunk = tid + i * NTHREADS;   // 8192 chunks of 8 floats
        int row = chunk >> 5;
        int c8  = chunk & 31;
        const f32x4* src = reinterpret_cast<const f32x4*>(W0 + row * DIM + c8 * 8);
        f32x4 f0 = src[0], f1 = src[1];
        bf16x8 w;
        w[0] = f2bf(f0[0]); w[1] = f2bf(f0[1]); w[2] = f2bf(f0[2]); w[3] = f2bf(f0[3]);
        w[4] = f2bf(f1[0]); w[5] = f2bf(f1[1]); w[6] = f2bf(f1[2]); w[7] = f2bf(f1[3]);
        int addr = row * 512 + ((c8 * 16) ^ ((row & 15) << 4));
        *reinterpret_cast<bf16x8*>(lds + addr) = w;
    }
    asm volatile("s_waitcnt vmcnt(0) lgkmcnt(0)" ::: "memory");
    __builtin_amdgcn_s_barrier();          // W visible to all waves

    const int l15 = lane & 15;
    const int lg  = lane >> 4;     // k-subgroup 0..3
    const int cg  = wave & 3;      // 64-chan group 0..3
    const int tg  = wave >> 2;     // 32-token half 0..1 of each 64-token round

    // ---- B into VGPRs once: 4 nt x 8 s x 16 B/lane = 128 VGPR ----
    bf16x8 Breg[4][8];
    #pragma unroll
    for (int nt = 0; nt < 4; ++nt)
        #pragma unroll
        for (int s = 0; s < 8; ++s)
            Breg[nt][s] = *reinterpret_cast<const bf16x8*>(
                lds + (cg * 64 + nt * 16 + l15) * 512 + ((s * 64 + lg * 16) ^ (l15 << 4)));
    asm volatile("s_waitcnt lgkmcnt(0)" ::: "memory");
    __builtin_amdgcn_s_barrier();          // all B-reads done: W region now dead,
                                           // A double-buffer overlays [0, 64 KB)

    // A-stage (round-10 proven): wave burst-loads rows srow..srow+7 (1 KB/inst)
    const int srow = wave * 8;
    const float* Xblk = X + (size_t)b * 1024 * DIM;
    float*       Oblk = Out + (size_t)b * 1024 * DIM;

    f32x4 Xrow[8];
    #define ALOAD(R) do {                                                      \
        _Pragma("unroll")                                                      \
        for (int jj = 0; jj < 8; ++jj)                                         \
            Xrow[jj] = gload4(Xblk + (size_t)((R) * 64 + srow + jj) * DIM      \
                              + lane * 4);                                     \
    } while (0)
    #define ASTORE(BUF) do {                                                   \
        _Pragma("unroll")                                                      \
        for (int jj = 0; jj < 8; ++jj) {                                       \
            int row_ = srow + jj;                                              \
            f32x4 xv = Xrow[jj];                                               \
            bf16x4 xw;                                                         \
            xw[0] = f2bf(xv[0]); xw[1] = f2bf(xv[1]);                          \
            xw[2] = f2bf(xv[2]); xw[3] = f2bf(xv[3]);                          \
            int dst = (BUF) * 32768 + row_ * 512                               \
                    + ((((lane >> 1) ^ (row_ & 15)) << 4)) + (lane & 1) * 8;   \
            *reinterpret_cast<bf16x4*>(lds + dst) = xw;                        \
        }                                                                      \
    } while (0)

    // prologue: A(0) staged into buf0, loads(1) in flight
    ALOAD(0);
    WAITV(0); __builtin_amdgcn_sched_barrier(0);
    ASTORE(0);
    ALOAD(1);
    asm volatile("s_waitcnt lgkmcnt(0)" ::: "memory");
    __builtin_amdgcn_s_barrier();

    for (int r = 0; r < NROUNDS; ++r) {
        const char* ab = lds + (r & 1) * 32768;

        f32x4 acc[2][4];
        #pragma unroll
        for (int mt = 0; mt < 2; ++mt)
            #pragma unroll
            for (int nt = 0; nt < 4; ++nt) acc[mt][nt] = (f32x4)0.0f;

        #pragma unroll
        for (int s = 0; s < 8; ++s) {
            bf16x8 a0 = *reinterpret_cast<const bf16x8*>(
                ab + (tg * 32 + l15) * 512      + ((s * 64 + lg * 16) ^ (l15 << 4)));
            bf16x8 a1 = *reinterpret_cast<const bf16x8*>(
                ab + (tg * 32 + 16 + l15) * 512 + ((s * 64 + lg * 16) ^ (l15 << 4)));
            #pragma unroll
            for (int nt = 0; nt < 4; ++nt) {
                acc[0][nt] = __builtin_amdgcn_mfma_f32_16x16x32_bf16(Breg[nt][s], a0, acc[0][nt], 0, 0, 0);
                acc[1][nt] = __builtin_amdgcn_mfma_f32_16x16x32_bf16(Breg[nt][s], a1, acc[1][nt], 0, 0, 0);
            }
        }

        // C stores: token = tg*32+mt*16+l15, chan = cg*64+nt*16+lg*4 (+reg)
        #pragma unroll
        for (int mt = 0; mt < 2; ++mt)
            #pragma unroll
            for (int nt = 0; nt < 4; ++nt) {
                float* o = Oblk + (size_t)(r * 64 + tg * 32 + mt * 16 + l15) * DIM
                         + cg * 64 + nt * 16 + lg * 4;
                *reinterpret_cast<f32x4*>(o) = acc[mt][nt];
            }

        if (r + 1 < NROUNDS) {
            // In flight: 8 loads(r+1) (oldest) + this round's 8 C-stores.
            // FIFO retirement (m135): vmcnt<=8 => oldest 8 = loads(r+1) done.
            WAITV(8);
            __builtin_amdgcn_sched_barrier(0);
            ASTORE((r + 1) & 1);        // consume Xrow BEFORE reloading it
            if (r + 2 < NROUNDS) ALOAD(r + 2);   // round-11 bug: this preceded
                                                 // ASTORE and clobbered Xrow
        }
        // One barrier/round: my ds-ops drained, then all waves rendezvous.
        asm volatile("s_waitcnt lgkmcnt(0)" ::: "memory");
        __builtin_amdgcn_s_barrier();
    }
    WAITV(0);   // drain tail stores before endpgm
    #undef ALOAD
    #undef ASTORE
}

extern "C" void kernel_launch(void* const* d_in, const int* in_sizes, int n_in,
                              void* d_out, int out_size, void* d_ws, size_t ws_size,
                              hipStream_t stream) {
    (void)in_sizes; (void)n_in; (void)d_ws; (void)ws_size; (void)out_size;
    const float* X = (const float*)d_in[0];
    const float* W = (const float*)d_in[1];   // [8,256,256]; expert 0 = first 65536
    float* Out = (float*)d_out;

    hipFuncSetAttribute((const void*)moe_expert0_kernel,
                        hipFuncAttributeMaxDynamicSharedMemorySize, LDS_BYTES);
    moe_expert0_kernel<<<dim3(NBLOCKS), dim3(NTHREADS), LDS_BYTES, stream>>>(X, W, Out);
}

// Round 13
// 111.759 us; speedup vs baseline: 1.0319x; 1.0319x over previous
//
#include <hip/hip_runtime.h>
#include <hip/hip_bf16.h>

typedef __attribute__((ext_vector_type(4))) float  f32x4;
typedef __attribute__((ext_vector_type(8))) short  bf16x8;
typedef __attribute__((ext_vector_type(4))) short  bf16x4;

#define DIM       256
#define NBLOCKS   256
#define NTHREADS  512
#define NROUNDS   16           // 64-token rounds per block (1024 tokens)
#define LDS_BYTES 131072       // W staging (128 KB), later overlaid by 2x32 KB A-bufs

#define WAITV(N) asm volatile("s_waitcnt vmcnt(" #N ")" ::: "memory")

__device__ __forceinline__ short f2bf(float x) {
    __hip_bfloat16 h = __float2bfloat16(x);
    return *reinterpret_cast<short*>(&h);
}

// Pinned-issue load; vmcnt retires FIFO (m135), so counted waits are exact.
__device__ __forceinline__ f32x4 gload4(const float* p) {
    f32x4 r;
    asm volatile("global_load_dwordx4 %0, %1, off" : "=v"(r) : "v"(p) : "memory");
    return r;
}

// out[n][o] = sum_k X[n][k] * W0[o][k]  (router is degenerate: expert 0 always)
__global__ __launch_bounds__(NTHREADS, 2)   // 256-VGPR cap (round-8 lesson)
void moe_expert0_kernel(const float* __restrict__ X,
                        const float* __restrict__ W0,
                        float* __restrict__ Out)
{
    extern __shared__ char lds[];
    const int tid  = threadIdx.x;
    const int lane = tid & 63;
    const int wave = tid >> 6;
    const int b    = blockIdx.x;

    // ---- stage full W (256x256) -> bf16, XOR-swizzled: row*512 + (cb ^ ((row&15)<<4))
    #pragma unroll
    for (int i = 0; i < 16; ++i) {
        int chunk = tid + i * NTHREADS;   // 8192 chunks of 8 floats
        int row = chunk >> 5;
        int c8  = chunk & 31;
        const f32x4* src = reinterpret_cast<const f32x4*>(W0 + row * DIM + c8 * 8);
        f32x4 f0 = src[0], f1 = src[1];
        bf16x8 w;
        w[0] = f2bf(f0[0]); w[1] = f2bf(f0[1]); w[2] = f2bf(f0[2]); w[3] = f2bf(f0[3]);
        w[4] = f2bf(f1[0]); w[5] = f2bf(f1[1]); w[6] = f2bf(f1[2]); w[7] = f2bf(f1[3]);
        int addr = row * 512 + ((c8 * 16) ^ ((row & 15) << 4));
        *reinterpret_cast<bf16x8*>(lds + addr) = w;
    }
    asm volatile("s_waitcnt vmcnt(0) lgkmcnt(0)" ::: "memory");
    __builtin_amdgcn_s_barrier();          // W visible to all waves

    const int l15 = lane & 15;
    const int lg  = lane >> 4;     // k-subgroup 0..3
    const int cg  = wave & 3;      // 64-chan group 0..3
    const int tg  = wave >> 2;     // 32-token half 0..1 of each 64-token round

    // ---- B into VGPRs once: 4 nt x 8 s x 16 B/lane = 128 VGPR ----
    bf16x8 Breg[4][8];
    #pragma unroll
    for (int nt = 0; nt < 4; ++nt)
        #pragma unroll
        for (int s = 0; s < 8; ++s)
            Breg[nt][s] = *reinterpret_cast<const bf16x8*>(
                lds + (cg * 64 + nt * 16 + l15) * 512 + ((s * 64 + lg * 16) ^ (l15 << 4)));
    asm volatile("s_waitcnt lgkmcnt(0)" ::: "memory");
    __builtin_amdgcn_s_barrier();          // all B-reads done: W region now dead,
                                           // A double-buffer overlays [0, 64 KB)

    // A-stage (round-10 proven): wave burst-loads rows srow..srow+7 (1 KB/inst)
    const int srow = wave * 8;
    const float* Xblk = X + (size_t)b * 1024 * DIM;
    float*       Oblk = Out + (size_t)b * 1024 * DIM;

    f32x4 Xrow[8];
    #define ALOAD(R) do {                                                      \
        _Pragma("unroll")                                                      \
        for (int jj = 0; jj < 8; ++jj)                                         \
            Xrow[jj] = gload4(Xblk + (size_t)((R) * 64 + srow + jj) * DIM      \
                              + lane * 4);                                     \
    } while (0)
    #define ASTORE(BUF) do {                                                   \
        _Pragma("unroll")                                                      \
        for (int jj = 0; jj < 8; ++jj) {                                       \
            int row_ = srow + jj;                                              \
            f32x4 xv = Xrow[jj];                                               \
            bf16x4 xw;                                                         \
            xw[0] = f2bf(xv[0]); xw[1] = f2bf(xv[1]);                          \
            xw[2] = f2bf(xv[2]); xw[3] = f2bf(xv[3]);                          \
            int dst = (BUF) * 32768 + row_ * 512                               \
                    + ((((lane >> 1) ^ (row_ & 15)) << 4)) + (lane & 1) * 8;   \
            *reinterpret_cast<bf16x4*>(lds + dst) = xw;                        \
        }                                                                      \
    } while (0)

    // prologue: A(0) staged into buf0, loads(1) in flight
    ALOAD(0);
    WAITV(0); __builtin_amdgcn_sched_barrier(0);
    ASTORE(0);
    ALOAD(1);
    asm volatile("s_waitcnt lgkmcnt(0)" ::: "memory");
    __builtin_amdgcn_s_barrier();

    for (int r = 0; r < NROUNDS; ++r) {
        const char* ab = lds + (r & 1) * 32768;

        f32x4 acc[2][4];
        #pragma unroll
        for (int mt = 0; mt < 2; ++mt)
            #pragma unroll
            for (int nt = 0; nt < 4; ++nt) acc[mt][nt] = (f32x4)0.0f;

        #pragma unroll
        for (int s = 0; s < 8; ++s) {
            bf16x8 a0 = *reinterpret_cast<const bf16x8*>(
                ab + (tg * 32 + l15) * 512      + ((s * 64 + lg * 16) ^ (l15 << 4)));
            bf16x8 a1 = *reinterpret_cast<const bf16x8*>(
                ab + (tg * 32 + 16 + l15) * 512 + ((s * 64 + lg * 16) ^ (l15 << 4)));
            #pragma unroll
            for (int nt = 0; nt < 4; ++nt) {
                acc[0][nt] = __builtin_amdgcn_mfma_f32_16x16x32_bf16(Breg[nt][s], a0, acc[0][nt], 0, 0, 0);
                acc[1][nt] = __builtin_amdgcn_mfma_f32_16x16x32_bf16(Breg[nt][s], a1, acc[1][nt], 0, 0, 0);
            }
        }

        // C stores: NON-TEMPORAL (nt bit). The 256-MB write stream is never
        // re-read; without nt it allocates in L3 and evicts X between graph
        // replays (measured FETCH ~132 MB = half of X re-fetched from HBM).
        // nt keeps X L3-resident: FETCH should drop toward ~0-70 MB.
        // token = tg*32+mt*16+l15, chan = cg*64+nt*16+lg*4 (+reg)
        #pragma unroll
        for (int mt = 0; mt < 2; ++mt)
            #pragma unroll
            for (int nt = 0; nt < 4; ++nt) {
                float* o = Oblk + (size_t)(r * 64 + tg * 32 + mt * 16 + l15) * DIM
                         + cg * 64 + nt * 16 + lg * 4;
                __builtin_nontemporal_store(acc[mt][nt], reinterpret_cast<f32x4*>(o));
            }

        if (r + 1 < NROUNDS) {
            // In flight: 8 loads(r+1) (oldest) + this round's 8 C-stores.
            // FIFO retirement (m135): vmcnt<=8 => oldest 8 = loads(r+1) done.
            WAITV(8);
            __builtin_amdgcn_sched_barrier(0);
            ASTORE((r + 1) & 1);        // consume Xrow BEFORE reloading it
            if (r + 2 < NROUNDS) ALOAD(r + 2);
        }
        // One barrier/round: my ds-ops drained, then all waves rendezvous.
        asm volatile("s_waitcnt lgkmcnt(0)" ::: "memory");
        __builtin_amdgcn_s_barrier();
    }
    WAITV(0);   // drain tail stores before endpgm
    #undef ALOAD
    #undef ASTORE
}

extern "C" void kernel_launch(void* const* d_in, const int* in_sizes, int n_in,
                              void* d_out, int out_size, void* d_ws, size_t ws_size,
                              hipStream_t stream) {
    (void)in_sizes; (void)n_in; (void)d_ws; (void)ws_size; (void)out_size;
    const float* X = (const float*)d_in[0];
    const float* W = (const float*)d_in[1];   // [8,256,256]; expert 0 = first 65536
    float* Out = (float*)d_out;

    hipFuncSetAttribute((const void*)moe_expert0_kernel,
                        hipFuncAttributeMaxDynamicSharedMemorySize, LDS_BYTES);
    moe_expert0_kernel<<<dim3(NBLOCKS), dim3(NTHREADS), LDS_BYTES, stream>>>(X, W, Out);
}

// Round 16
// 91.286 us; speedup vs baseline: 1.2633x; 1.2243x over previous
//
#include <hip/hip_runtime.h>
#include <hip/hip_bf16.h>

typedef __attribute__((ext_vector_type(4))) float  f32x4;
typedef __attribute__((ext_vector_type(8))) short  bf16x8;
typedef __attribute__((ext_vector_type(4))) short  bf16x4;

#define DIM       256
#define NBLOCKS   256
#define NTHREADS  512
#define NROUNDS   16           // 64-token rounds per block (1024 tokens)
#define CBASE     65536        // C-buf: 64 rows x 1 KB fp32, swizzled 16-B slots
#define LDS_BYTES 131072       // W staging 128K; later: A 2x32K [0,64K) + C 64K

#define WAITV(N) asm volatile("s_waitcnt vmcnt(" #N ")" ::: "memory")

__device__ __forceinline__ short f2bf(float x) {
    __hip_bfloat16 h = __float2bfloat16(x);
    return *reinterpret_cast<short*>(&h);
}

// Pinned-issue load; vmcnt retires FIFO (m135), so counted waits are exact.
__device__ __forceinline__ f32x4 gload4(const float* p) {
    f32x4 r;
    asm volatile("global_load_dwordx4 %0, %1, off" : "=v"(r) : "v"(p) : "memory");
    return r;
}

// out[n][o] = sum_k X[n][k] * W0[o][k]  (router is degenerate: expert 0 always)
__global__ __launch_bounds__(NTHREADS, 2)   // 256-VGPR cap (round-8 lesson)
void moe_expert0_kernel(const float* __restrict__ X,
                        const float* __restrict__ W0,
                        float* __restrict__ Out)
{
    extern __shared__ char lds[];
    const int tid  = threadIdx.x;
    const int lane = tid & 63;
    const int wave = tid >> 6;
    const int b    = blockIdx.x;

    // ---- stage full W (256x256) -> bf16, XOR-swizzled: row*512 + (cb ^ ((row&15)<<4))
    #pragma unroll
    for (int i = 0; i < 16; ++i) {
        int chunk = tid + i * NTHREADS;   // 8192 chunks of 8 floats
        int row = chunk >> 5;
        int c8  = chunk & 31;
        const f32x4* src = reinterpret_cast<const f32x4*>(W0 + row * DIM + c8 * 8);
        f32x4 f0 = src[0], f1 = src[1];
        bf16x8 w;
        w[0] = f2bf(f0[0]); w[1] = f2bf(f0[1]); w[2] = f2bf(f0[2]); w[3] = f2bf(f0[3]);
        w[4] = f2bf(f1[0]); w[5] = f2bf(f1[1]); w[6] = f2bf(f1[2]); w[7] = f2bf(f1[3]);
        int addr = row * 512 + ((c8 * 16) ^ ((row & 15) << 4));
        *reinterpret_cast<bf16x8*>(lds + addr) = w;
    }
    asm volatile("s_waitcnt vmcnt(0) lgkmcnt(0)" ::: "memory");
    __builtin_amdgcn_s_barrier();          // W visible to all waves

    const int l15 = lane & 15;
    const int lg  = lane >> 4;     // k-subgroup 0..3
    const int cg  = wave & 3;      // 64-chan group 0..3
    const int tg  = wave >> 2;     // 32-token half 0..1 of each 64-token round

    // ---- B into VGPRs once: 4 nt x 8 s x 16 B/lane = 128 VGPR (r12-proven) ----
    bf16x8 Breg[4][8];
    #pragma unroll
    for (int nt = 0; nt < 4; ++nt)
        #pragma unroll
        for (int s = 0; s < 8; ++s)
            Breg[nt][s] = *reinterpret_cast<const bf16x8*>(
                lds + (cg * 64 + nt * 16 + l15) * 512 + ((s * 64 + lg * 16) ^ (l15 << 4)));
    asm volatile("s_waitcnt lgkmcnt(0)" ::: "memory");
    __builtin_amdgcn_s_barrier();          // W region dead: A-bufs overlay [0,64K),
                                           // C-buf lives at [64K,128K)

    // A-stage (round-10 proven): wave burst-loads rows srow..srow+7 (1 KB/inst)
    const int srow = wave * 8;
    const float* Xblk = X + (size_t)b * 1024 * DIM;
    float*       Oblk = Out + (size_t)b * 1024 * DIM;

    f32x4 Xrow[8];
    #define ALOAD(R) do {                                                      \
        int rr_ = (R) > NROUNDS - 1 ? NROUNDS - 1 : (R);                       \
        _Pragma("unroll")                                                      \
        for (int jj = 0; jj < 8; ++jj)                                         \
            Xrow[jj] = gload4(Xblk + (size_t)(rr_ * 64 + srow + jj) * DIM      \
                              + lane * 4);                                     \
    } while (0)
    #define ASTORE(BUF) do {                                                   \
        _Pragma("unroll")                                                      \
        for (int jj = 0; jj < 8; ++jj) {                                       \
            int row_ = srow + jj;                                              \
            f32x4 xv = Xrow[jj];                                               \
            bf16x4 xw;                                                         \
            xw[0] = f2bf(xv[0]); xw[1] = f2bf(xv[1]);                          \
            xw[2] = f2bf(xv[2]); xw[3] = f2bf(xv[3]);                          \
            int dst = (BUF) * 32768 + row_ * 512                               \
                    + ((((lane >> 1) ^ (row_ & 15)) << 4)) + (lane & 1) * 8;   \
            *reinterpret_cast<bf16x4*>(lds + dst) = xw;                        \
        }                                                                      \
    } while (0)

    // prologue: A(0) staged into buf0, loads(1) in flight
    ALOAD(0);
    WAITV(0); __builtin_amdgcn_sched_barrier(0);
    ASTORE(0);
    ALOAD(1);
    asm volatile("s_waitcnt lgkmcnt(0)" ::: "memory");
    __builtin_amdgcn_s_barrier();

    for (int r = 0; r < NROUNDS; ++r) {
        const char* ab = lds + (r & 1) * 32768;

        f32x4 acc[2][4];
        #pragma unroll
        for (int mt = 0; mt < 2; ++mt)
            #pragma unroll
            for (int nt = 0; nt < 4; ++nt) acc[mt][nt] = (f32x4)0.0f;

        #pragma unroll
        for (int s = 0; s < 8; ++s) {
            bf16x8 a0 = *reinterpret_cast<const bf16x8*>(
                ab + (tg * 32 + l15) * 512      + ((s * 64 + lg * 16) ^ (l15 << 4)));
            bf16x8 a1 = *reinterpret_cast<const bf16x8*>(
                ab + (tg * 32 + 16 + l15) * 512 + ((s * 64 + lg * 16) ^ (l15 << 4)));
            #pragma unroll
            for (int nt = 0; nt < 4; ++nt) {
                acc[0][nt] = __builtin_amdgcn_mfma_f32_16x16x32_bf16(Breg[nt][s], a0, acc[0][nt], 0, 0, 0);
                acc[1][nt] = __builtin_amdgcn_mfma_f32_16x16x32_bf16(Breg[nt][s], a1, acc[1][nt], 0, 0, 0);
            }
        }

        // ds_write acc -> C-buf, 16-B slot swizzle (slot = sc ^ (row&7)):
        // token row = tg*32+mt*16+l15, slot sc = cg*16+nt*4+lg. Bank-floor on
        // both sides (8 lanes/bank-set write, pure permutation read).
        #pragma unroll
        for (int mt = 0; mt < 2; ++mt)
            #pragma unroll
            for (int nt = 0; nt < 4; ++nt) {
                int row_ = tg * 32 + mt * 16 + l15;
                int sc   = cg * 16 + nt * 4 + lg;
                int dst  = CBASE + row_ * 1024 + ((sc ^ (row_ & 7)) << 4);
                *reinterpret_cast<f32x4*>(lds + dst) = acc[mt][nt];
            }

        if (r + 1 < NROUNDS) {
            // r==0: FIFO holds only the 8 loads(1) (no stores yet) -> WAITV(8)
            // would pass vacuously; drain fully. r>=1: FIFO = [8 loads(r+1)]
            // [8 burst-stores(r-1)]; vmcnt<=8 => oldest 8 = loads retired
            // (r10/12/13-proven pattern).
            if (r) { WAITV(8); } else { WAITV(0); }
            __builtin_amdgcn_sched_barrier(0);
            ASTORE((r + 1) & 1);        // consume Xrow BEFORE reloading it (r11)
            ALOAD(r + 2);
        }
        asm volatile("s_waitcnt lgkmcnt(0)" ::: "memory");
        __builtin_amdgcn_s_barrier();   // #1: C(r) complete + A(r+1) visible

        // burst C(r): wave owns rows srow..srow+7; ONE contiguous 1-KB nt
        // store per row (fill-kernel shape, no 64-B write amplification).
        #pragma unroll
        for (int jj = 0; jj < 8; ++jj) {
            int row_ = srow + jj;
            f32x4 v = *reinterpret_cast<const f32x4*>(
                lds + CBASE + row_ * 1024 + ((lane << 4) ^ ((row_ & 7) << 4)));
            __builtin_nontemporal_store(v, reinterpret_cast<f32x4*>(
                Oblk + (size_t)(r * 64 + row_) * DIM + lane * 4));
        }
        asm volatile("" ::: "memory");  // pin burst reads/stores before barrier
        __builtin_amdgcn_s_barrier();   // #2: C-buf free for round r+1
    }
    WAITV(0);   // drain tail prefetches/stores before endpgm
    #undef ALOAD
    #undef ASTORE
}

extern "C" void kernel_launch(void* const* d_in, const int* in_sizes, int n_in,
                              void* d_out, int out_size, void* d_ws, size_t ws_size,
                              hipStream_t stream) {
    (void)in_sizes; (void)n_in; (void)d_ws; (void)ws_size; (void)out_size;
    const float* X = (const float*)d_in[0];
    const float* W = (const float*)d_in[1];   // [8,256,256]; expert 0 = first 65536
    float* Out = (float*)d_out;

    hipFuncSetAttribute((const void*)moe_expert0_kernel,
                        hipFuncAttributeMaxDynamicSharedMemorySize, LDS_BYTES);
    moe_expert0_kernel<<<dim3(NBLOCKS), dim3(NTHREADS), LDS_BYTES, stream>>>(X, W, Out);
}